// Round 9
// baseline (1251.019 us; speedup 1.0000x reference)
//
#include <hip/hip_runtime.h>
#include <hip/hip_bf16.h>

#define L_ 2
#define D_ 512
#define H_ 8
#define DK_ 64
#define F_ 2048
#define E_ 8
#define V_ 32000
#define B_ 2
#define S_ 1024
#define T_ 1024
#define NTOK (B_*S_)
#define MAXPAD 5120            // per-expert 128-padded total upper bound
#define RBLK   40              // MAXPAD/128
#define QLD 1536

typedef unsigned short u16;
typedef _Float16 f16x8 __attribute__((ext_vector_type(8)));
typedef _Float16 f16x4 __attribute__((ext_vector_type(4)));
typedef float f32x4 __attribute__((ext_vector_type(4)));

__device__ __forceinline__ void gload16(const void* g, const void* l) {
    __builtin_amdgcn_global_load_lds(
        (const __attribute__((address_space(1))) void*)g,
        (__attribute__((address_space(3))) void*)l, 16, 0, 0);
}

__device__ __forceinline__ void split_f16(float v, _Float16& h, _Float16& l) {
    h = (_Float16)v;
    l = (_Float16)(v - (float)h);
}

// ---------------------------------------------------------------- embedding + PE (hi/lo f16 only)
__global__ __launch_bounds__(256) void embed_pe(const int* __restrict__ toks,
                                                const float* __restrict__ emb,
                                                _Float16* __restrict__ oh,
                                                _Float16* __restrict__ ol, int Slen)
{
    int n = blockIdx.x;
    int spos = n % Slen;
    int tok = toks[n];
    const float* erow = emb + (size_t)tok * D_;
    size_t rb = (size_t)n * D_;
    for (int j = threadIdx.x; j < D_; j += 256) {
        int i = j >> 1;
        float arg = (float)spos * expf(-(float)i * 0.035977892f);
        float pe = (j & 1) ? cosf(arg) : sinf(arg);
        float v = erow[j] + pe;
        _Float16 h, l; split_f16(v, h, l);
        oh[rb + j] = h; ol[rb + j] = l;
    }
}

// ---------------------------------------------------------------- weight transpose f32[R][C] -> f16 hi/lo [C][R]
template<bool WLO>
__global__ __launch_bounds__(256) void transpose_w(const float* __restrict__ in,
                                                   _Float16* __restrict__ oh,
                                                   _Float16* __restrict__ ol, int R, int C)
{
    __shared__ float t[64][65];
    size_t sb = (size_t)blockIdx.z * R * C;
    in += sb; oh += sb; if (WLO) ol += sb;
    int c0 = blockIdx.x * 64, r0 = blockIdx.y * 64;
    int tid = threadIdx.x;
    {
        int r = tid >> 4;
        int cq = (tid & 15) * 4;
        #pragma unroll
        for (int p = 0; p < 4; ++p) {
            int rr = r + p * 16;
            float4 v = *(const float4*)&in[(size_t)(r0 + rr) * C + c0 + cq];
            t[rr][cq] = v.x; t[rr][cq + 1] = v.y; t[rr][cq + 2] = v.z; t[rr][cq + 3] = v.w;
        }
    }
    __syncthreads();
    int rp = (tid & 15) * 4;
    int cb = tid >> 4;
    #pragma unroll
    for (int p = 0; p < 4; ++p) {
        int c = cb + p * 16;
        f16x4 hv, lv;
        #pragma unroll
        for (int j = 0; j < 4; ++j) {
            float v = t[rp + j][c];
            _Float16 h = (_Float16)v;
            hv[j] = h;
            if (WLO) lv[j] = (_Float16)(v - (float)h);
        }
        *(f16x4*)&oh[(size_t)(c0 + c) * R + r0 + rp] = hv;
        if (WLO) *(f16x4*)&ol[(size_t)(c0 + c) * R + r0 + rp] = lv;
    }
}

// 3 attn-weight sets (D x D, 8 matrices each) in one launch; z: set = z>>3, sub = z&7
__global__ __launch_bounds__(256) void transpose_w3(
    const float* __restrict__ i0, _Float16* __restrict__ h0, _Float16* __restrict__ l0,
    const float* __restrict__ i1, _Float16* __restrict__ h1, _Float16* __restrict__ l1,
    const float* __restrict__ i2, _Float16* __restrict__ h2, _Float16* __restrict__ l2)
{
    __shared__ float t[64][65];
    int set = blockIdx.z >> 3, sub = blockIdx.z & 7;
    const float* in = (set == 0) ? i0 : (set == 1) ? i1 : i2;
    _Float16* oh = (set == 0) ? h0 : (set == 1) ? h1 : h2;
    _Float16* ol = (set == 0) ? l0 : (set == 1) ? l1 : l2;
    size_t sb = (size_t)sub * D_ * D_;
    in += sb; oh += sb; ol += sb;
    int c0 = blockIdx.x * 64, r0 = blockIdx.y * 64;
    int tid = threadIdx.x;
    {
        int r = tid >> 4;
        int cq = (tid & 15) * 4;
        #pragma unroll
        for (int p = 0; p < 4; ++p) {
            int rr = r + p * 16;
            float4 v = *(const float4*)&in[(size_t)(r0 + rr) * D_ + c0 + cq];
            t[rr][cq] = v.x; t[rr][cq + 1] = v.y; t[rr][cq + 2] = v.z; t[rr][cq + 3] = v.w;
        }
    }
    __syncthreads();
    int rp = (tid & 15) * 4;
    int cb = tid >> 4;
    #pragma unroll
    for (int p = 0; p < 4; ++p) {
        int c = cb + p * 16;
        f16x4 hv, lv;
        #pragma unroll
        for (int j = 0; j < 4; ++j) {
            float v = t[rp + j][c];
            _Float16 h = (_Float16)v;
            hv[j] = h;
            lv[j] = (_Float16)(v - (float)h);
        }
        *(f16x4*)&oh[(size_t)(c0 + c) * D_ + r0 + rp] = hv;
        *(f16x4*)&ol[(size_t)(c0 + c) * D_ + r0 + rp] = lv;
    }
}

// ---------------------------------------------------------------- MFMA GEMM (tile-templated)
// SWZ: XCD-bijective block remap (requires gridDim.x*gridDim.y % 8 == 0)
template<int MODE, bool RELU, int OUTMODE, int PASSES, int TM, int TN, bool SWZ>
__global__ __launch_bounds__(256, 2) void gemm_mfma(
    const _Float16* __restrict__ Ah, const _Float16* __restrict__ Al,
    const _Float16* __restrict__ Wh, const _Float16* __restrict__ Wl,
    const float* __restrict__ biasbase,
    float* __restrict__ Cf, _Float16* __restrict__ Ch, _Float16* __restrict__ Cl,
    _Float16* __restrict__ vt_h, _Float16* __restrict__ vt_l, int cbase,
    int M, int Kd, int N, int ldc,
    const int* __restrict__ route_tok, const int* __restrict__ rb_expert,
    const int* __restrict__ pad_base, const int* __restrict__ counts)
{
    constexpr int AR = TM / 32;
    constexpr int BR = TN / 32;
    int bx = blockIdx.x, by = blockIdx.y;
    if (SWZ) {
        int total = gridDim.x * gridDim.y;
        int n = by * gridDim.x + bx;
        int q = total >> 3;
        int w2 = (n & 7) * q + (n >> 3);
        bx = w2 % gridDim.x; by = w2 / gridDim.x;
    }
    int row0 = bx * TM;
    const _Float16* Wmh = Wh;
    const _Float16* Wml = Wl;
    const float* bias = biasbase;
    int vend = M;
    if (MODE != 0) {
        int total = pad_base[E_];
        if (row0 >= total) return;
        int e = rb_expert[row0 >> 7];
        vend = pad_base[e] + counts[e];
        Wmh = Wh + (size_t)e * Kd * N;
        if (PASSES == 3) Wml = Wl + (size_t)e * Kd * N;
        bias = biasbase + (size_t)e * N;
    }
    int col0 = by * TN;
    int tid = threadIdx.x;
    int lane = tid & 63, w = tid >> 6;
    int wm = w >> 1, wn = w & 1;

    __shared__ _Float16 lds[(PASSES == 3 ? 2 : 1) * (TM + TN) * 64];
    _Float16* lAh = lds;
    _Float16* lBh = lds + TM * 64;
    _Float16* lAl = (PASSES == 3) ? lds + (TM + TN) * 64 : nullptr;
    _Float16* lBl = (PASSES == 3) ? lds + (TM + TN) * 64 + TM * 64 : nullptr;

    int srow8 = lane >> 3;
    int q8 = lane & 7;
    size_t aoff[AR], boff[BR];
    #pragma unroll
    for (int j = 0; j < AR; ++j) {
        int m = w * (TM / 4) + j * 8 + srow8;
        int gr = row0 + m;
        int ar = (MODE == 1) ? route_tok[gr] : gr;
        int ss = (q8 ^ (m & 7)) << 3;
        aoff[j] = (size_t)ar * Kd + ss;
    }
    #pragma unroll
    for (int j = 0; j < BR; ++j) {
        int m = w * (TN / 4) + j * 8 + srow8;
        int ss = (q8 ^ (m & 7)) << 3;
        boff[j] = (size_t)(col0 + m) * Kd + ss;
    }

    f32x4 zero4 = {0.f, 0.f, 0.f, 0.f};
    f32x4 acc[AR][BR];
    #pragma unroll
    for (int i = 0; i < AR; ++i)
        #pragma unroll
        for (int j = 0; j < BR; ++j) acc[i][j] = zero4;

    int lm = lane & 15, kg = lane >> 4;

    for (int k0 = 0; k0 < Kd; k0 += 64) {
        #pragma unroll
        for (int j = 0; j < AR; ++j) {
            int lb = (w * (TM / 4) + j * 8) * 64;
            gload16(Ah + aoff[j] + k0, lAh + lb);
            if (PASSES == 3) gload16(Al + aoff[j] + k0, lAl + lb);
        }
        #pragma unroll
        for (int j = 0; j < BR; ++j) {
            int lb = (w * (TN / 4) + j * 8) * 64;
            gload16(Wmh + boff[j] + k0, lBh + lb);
            if (PASSES == 3) gload16(Wml + boff[j] + k0, lBl + lb);
        }
        __syncthreads();
        #pragma unroll
        for (int ks = 0; ks < 2; ++ks) {
            f16x8 ah[AR], bh[BR];
            #pragma unroll
            for (int i = 0; i < AR; ++i) {
                int m = wm * (TM / 2) + i * 16 + lm;
                ah[i] = *(const f16x8*)&lAh[m * 64 + ((((ks << 2) + kg) ^ (m & 7)) << 3)];
            }
            #pragma unroll
            for (int j = 0; j < BR; ++j) {
                int n = wn * (TN / 2) + j * 16 + lm;
                bh[j] = *(const f16x8*)&lBh[n * 64 + ((((ks << 2) + kg) ^ (n & 7)) << 3)];
            }
            #pragma unroll
            for (int i = 0; i < AR; ++i)
                #pragma unroll
                for (int jn = 0; jn < BR; ++jn)
                    acc[i][jn] = __builtin_amdgcn_mfma_f32_16x16x32_f16(ah[i], bh[jn], acc[i][jn], 0, 0, 0);
            if (PASSES == 3) {
                f16x8 bl[BR];
                #pragma unroll
                for (int j = 0; j < BR; ++j) {
                    int n = wn * (TN / 2) + j * 16 + lm;
                    bl[j] = *(const f16x8*)&lBl[n * 64 + ((((ks << 2) + kg) ^ (n & 7)) << 3)];
                }
                #pragma unroll
                for (int i = 0; i < AR; ++i)
                    #pragma unroll
                    for (int jn = 0; jn < BR; ++jn)
                        acc[i][jn] = __builtin_amdgcn_mfma_f32_16x16x32_f16(ah[i], bl[jn], acc[i][jn], 0, 0, 0);
                f16x8 al[AR];
                #pragma unroll
                for (int i = 0; i < AR; ++i) {
                    int m = wm * (TM / 2) + i * 16 + lm;
                    al[i] = *(const f16x8*)&lAl[m * 64 + ((((ks << 2) + kg) ^ (m & 7)) << 3)];
                }
                #pragma unroll
                for (int i = 0; i < AR; ++i)
                    #pragma unroll
                    for (int jn = 0; jn < BR; ++jn)
                        acc[i][jn] = __builtin_amdgcn_mfma_f32_16x16x32_f16(al[i], bh[jn], acc[i][jn], 0, 0, 0);
            }
        }
        __syncthreads();
    }

    float bv[BR];
    #pragma unroll
    for (int jn = 0; jn < BR; ++jn) bv[jn] = bias[col0 + wn * (TN / 2) + jn * 16 + lm];
    int rowb = row0 + wm * (TM / 2) + (lane >> 4) * 4;

    if (OUTMODE == 2 && (col0 + cbase) >= 1024) {
        #pragma unroll
        for (int i = 0; i < AR; ++i) {
            int row = rowb + i * 16;
            int b = row >> 10, q = row & 1023;
            #pragma unroll
            for (int jn = 0; jn < BR; ++jn) {
                int vcol = col0 + cbase - 1024 + wn * (TN / 2) + jn * 16 + lm;
                int hh = vcol >> 6, dd = vcol & 63;
                f16x4 hv, lv;
                #pragma unroll
                for (int r = 0; r < 4; ++r) {
                    float v = acc[i][jn][r] + bv[jn];
                    _Float16 x1, x2; split_f16(v, x1, x2);
                    hv[r] = x1; lv[r] = x2;
                }
                size_t vtoff = ((size_t)((b << 3) + hh) * 64 + dd) * 1024 + q;
                *(f16x4*)&vt_h[vtoff] = hv;
                *(f16x4*)&vt_l[vtoff] = lv;
            }
        }
        return;
    }

    #pragma unroll
    for (int i = 0; i < AR; ++i) {
        #pragma unroll
        for (int r = 0; r < 4; ++r) {
            int row = rowb + i * 16 + r;
            if (MODE != 0 && row >= vend) continue;
            #pragma unroll
            for (int jn = 0; jn < BR; ++jn) {
                float v = acc[i][jn][r] + bv[jn];
                if (RELU) v = fmaxf(v, 0.f);
                int c = col0 + wn * (TN / 2) + jn * 16 + lm;
                if (OUTMODE == 0) {
                    Cf[(size_t)row * ldc + c] = v;
                } else {
                    _Float16 h, l; split_f16(v, h, l);
                    Ch[(size_t)row * ldc + cbase + c] = h;
                    Cl[(size_t)row * ldc + cbase + c] = l;
                }
            }
        }
    }
}

// ---------------------------------------------------------------- flash attention, 8-wave split-K
template<int CAUSAL>
__global__ __launch_bounds__(512, 1) void attn_flash(
    const _Float16* __restrict__ qkvh, const _Float16* __restrict__ qkvl,
    const _Float16* __restrict__ vth, const _Float16* __restrict__ vtl,
    const int* __restrict__ ktoks,
    _Float16* __restrict__ ch, _Float16* __restrict__ cl)
{
    int q0 = blockIdx.x * 64;
    int bh = blockIdx.y, b = bh >> 3, h = bh & 7;
    int tid = threadIdx.x, lane = tid & 63, w = tid >> 6;
    int qg = w & 3, kh = w >> 2;
    int lm = lane & 15, kg = lane >> 4;
    int srow8 = lane >> 3, q8 = lane & 7;
    int tb = b * S_;

    __shared__ _Float16 smem[49152];
    _Float16* hb  = smem + kh * 16384;
    _Float16* lKh = hb;
    _Float16* lKl = hb + 4096;
    _Float16* lVh = hb + 8192;
    _Float16* lVl = hb + 12288;
    _Float16* lPh = smem + 32768 + w * 1024;
    _Float16* lPl = smem + 40960 + w * 1024;

    size_t qbase = (size_t)b * S_ * QLD + h * DK_;
    const _Float16* Qh = qkvh + qbase;
    const _Float16* Ql = qkvl + qbase;
    const _Float16* Kh = qkvh + qbase + 512;
    const _Float16* Kl = qkvl + qbase + 512;
    const _Float16* Vh = vth + (size_t)bh * 64 * 1024;
    const _Float16* Vl = vtl + (size_t)bh * 64 * 1024;

    f16x8 qfh[2], qfl[2];
    {
        int qr = q0 + qg * 16 + lm;
        #pragma unroll
        for (int ks = 0; ks < 2; ++ks) {
            qfh[ks] = *(const f16x8*)&Qh[(size_t)qr * QLD + ks * 32 + kg * 8];
            qfl[ks] = *(const f16x8*)&Ql[(size_t)qr * QLD + ks * 32 + kg * 8];
        }
    }

    float mreg[4], lreg[4];
    f32x4 od[4];
    f32x4 zero4 = {0.f, 0.f, 0.f, 0.f};
    #pragma unroll
    for (int r = 0; r < 4; ++r) { mreg[r] = -1e30f; lreg[r] = 0.f; }
    #pragma unroll
    for (int jn = 0; jn < 4; ++jn) od[jn] = zero4;

    int qrow[4];
    #pragma unroll
    for (int r = 0; r < 4; ++r) qrow[r] = q0 + qg * 16 + (lane >> 4) * 4 + r;

    int nkt = CAUSAL ? (q0 >> 6) + 1 : 16;
    int nhalf = (nkt + 1) >> 1;

    for (int it = 0; it < nhalf; ++it) {
        int kt = 2 * it + kh;
        bool active = kt < nkt;
        int k0 = kt * 64;

        if (active) {
            #pragma unroll
            for (int j = 0; j < 2; ++j) {
                int row = qg * 16 + j * 8 + srow8;
                int lb = (qg * 16 + j * 8) * 64;
                int ss = (q8 ^ (row & 7)) << 3;
                gload16(Kh + (size_t)(k0 + row) * QLD + ss, lKh + lb);
                gload16(Kl + (size_t)(k0 + row) * QLD + ss, lKl + lb);
                gload16(Vh + (size_t)row * 1024 + k0 + ss, lVh + lb);
                gload16(Vl + (size_t)row * 1024 + k0 + ss, lVl + lb);
            }
        }
        __syncthreads();

        if (active) {
            bool diag = CAUSAL && (kt == (q0 >> 6));
            f32x4 accs[4];
            #pragma unroll
            for (int jn = 0; jn < 4; ++jn) accs[jn] = zero4;
            #pragma unroll
            for (int ks = 0; ks < 2; ++ks) {
                #pragma unroll
                for (int jn = 0; jn < 4; ++jn) {
                    int n = jn * 16 + lm;
                    int koff = n * 64 + ((((ks << 2) + kg) ^ (n & 7)) << 3);
                    f16x8 bhv = *(const f16x8*)&lKh[koff];
                    f16x8 blv = *(const f16x8*)&lKl[koff];
                    accs[jn] = __builtin_amdgcn_mfma_f32_16x16x32_f16(qfh[ks], bhv, accs[jn], 0, 0, 0);
                    accs[jn] = __builtin_amdgcn_mfma_f32_16x16x32_f16(qfh[ks], blv, accs[jn], 0, 0, 0);
                    accs[jn] = __builtin_amdgcn_mfma_f32_16x16x32_f16(qfl[ks], bhv, accs[jn], 0, 0, 0);
                }
            }

            float sv[4][4];
            #pragma unroll
            for (int jn = 0; jn < 4; ++jn) {
                int kglob = k0 + jn * 16 + lm;
                bool pad_ok = (ktoks[tb + kglob] != 0);
                #pragma unroll
                for (int r = 0; r < 4; ++r) {
                    float s = accs[jn][r] * 0.125f;
                    bool keep = pad_ok && (!diag || kglob <= qrow[r]);
                    sv[jn][r] = keep ? s : -1e9f;
                }
            }
            float pv[4][4];
            #pragma unroll
            for (int r = 0; r < 4; ++r) {
                float tm = fmaxf(fmaxf(sv[0][r], sv[1][r]), fmaxf(sv[2][r], sv[3][r]));
                tm = fmaxf(tm, __shfl_xor(tm, 1));
                tm = fmaxf(tm, __shfl_xor(tm, 2));
                tm = fmaxf(tm, __shfl_xor(tm, 4));
                tm = fmaxf(tm, __shfl_xor(tm, 8));
                float mnew = fmaxf(mreg[r], tm);
                float corr = expf(mreg[r] - mnew);
                lreg[r] *= corr;
                #pragma unroll
                for (int jn = 0; jn < 4; ++jn) od[jn][r] *= corr;
                float psum = 0.f;
                #pragma unroll
                for (int jn = 0; jn < 4; ++jn) {
                    float p = expf(sv[jn][r] - mnew);
                    pv[jn][r] = p;
                    psum += p;
                }
                psum += __shfl_xor(psum, 1);
                psum += __shfl_xor(psum, 2);
                psum += __shfl_xor(psum, 4);
                psum += __shfl_xor(psum, 8);
                lreg[r] += psum;
                mreg[r] = mnew;
            }

            #pragma unroll
            for (int jn = 0; jn < 4; ++jn) {
                int col = jn * 16 + lm;
                #pragma unroll
                for (int r = 0; r < 4; ++r) {
                    int rr = (lane >> 4) * 4 + r;
                    int idx = rr * 64 + (((col >> 3) ^ (rr & 7)) << 3) + (col & 7);
                    _Float16 hh, ll; split_f16(pv[jn][r], hh, ll);
                    lPh[idx] = hh; lPl[idx] = ll;
                }
            }

            #pragma unroll
            for (int ks = 0; ks < 2; ++ks) {
                int poff = lm * 64 + ((((ks << 2) + kg) ^ (lm & 7)) << 3);
                f16x8 pah = *(const f16x8*)&lPh[poff];
                f16x8 pal = *(const f16x8*)&lPl[poff];
                #pragma unroll
                for (int jn = 0; jn < 4; ++jn) {
                    int n = jn * 16 + lm;
                    int noff = n * 64 + ((((ks << 2) + kg) ^ (n & 7)) << 3);
                    f16x8 vbh = *(const f16x8*)&lVh[noff];
                    f16x8 vbl = *(const f16x8*)&lVl[noff];
                    od[jn] = __builtin_amdgcn_mfma_f32_16x16x32_f16(pah, vbh, od[jn], 0, 0, 0);
                    od[jn] = __builtin_amdgcn_mfma_f32_16x16x32_f16(pah, vbl, od[jn], 0, 0, 0);
                    od[jn] = __builtin_amdgcn_mfma_f32_16x16x32_f16(pal, vbh, od[jn], 0, 0, 0);
                }
            }
        }
        __syncthreads();
    }

    float* mrg = (float*)(smem + 32768);
    if (kh == 1) {
        float* mp = mrg + ((size_t)qg * 64 + lane) * 24;
        #pragma unroll
        for (int jn = 0; jn < 4; ++jn)
            #pragma unroll
            for (int r = 0; r < 4; ++r) mp[jn * 4 + r] = od[jn][r];
        #pragma unroll
        for (int r = 0; r < 4; ++r) { mp[16 + r] = mreg[r]; mp[20 + r] = lreg[r]; }
    }
    __syncthreads();
    if (kh == 0) {
        float* mp = mrg + ((size_t)qg * 64 + lane) * 24;
        #pragma unroll
        for (int r = 0; r < 4; ++r) {
            float m1 = mp[16 + r], l1 = mp[20 + r];
            float m = fmaxf(mreg[r], m1);
            float c0 = expf(mreg[r] - m), c1 = expf(m1 - m);
            float inv = 1.0f / (lreg[r] * c0 + l1 * c1);
            size_t rbase = (size_t)(tb + qrow[r]) * D_ + h * DK_;
            #pragma unroll
            for (int jn = 0; jn < 4; ++jn) {
                float o = (od[jn][r] * c0 + mp[jn * 4 + r] * c1) * inv;
                _Float16 hh, ll; split_f16(o, hh, ll);
                int d = jn * 16 + lm;
                ch[rbase + d] = hh; cl[rbase + d] = ll;
            }
        }
    }
}

// ---------------------------------------------------------------- residual + LN (+ optional fused gate logits)
template<bool GATE>
__global__ __launch_bounds__(256) void ln_add(const _Float16* __restrict__ xh,
                                              const _Float16* __restrict__ xl,
                                              const float* __restrict__ r,
                                              const float* __restrict__ g,
                                              const float* __restrict__ be,
                                              _Float16* __restrict__ oh,
                                              _Float16* __restrict__ ol,
                                              const float* __restrict__ gw,
                                              const float* __restrict__ gb,
                                              float* __restrict__ lg)
{
    int row = blockIdx.x;
    size_t rb = (size_t)row * D_;
    int tid = threadIdx.x;
    float v0 = (float)xh[rb + tid] + (float)xl[rb + tid] + r[rb + tid];
    float v1 = (float)xh[rb + tid + 256] + (float)xl[rb + tid + 256] + r[rb + tid + 256];
    float s = v0 + v1;
    for (int off = 32; off; off >>= 1) s += __shfl_down(s, off);
    __shared__ float red[8];
    __shared__ float gred[4][E_];
    int lane = tid & 63, wid = tid >> 6;
    if (!lane) red[wid] = s;
    __syncthreads();
    if (!tid) red[4] = (red[0] + red[1] + red[2] + red[3]) * (1.0f / 512.0f);
    __syncthreads();
    float m = red[4];
    float d0 = v0 - m, d1 = v1 - m;
    s = d0 * d0 + d1 * d1;
    for (int off = 32; off; off >>= 1) s += __shfl_down(s, off);
    if (!lane) red[wid] = s;
    __syncthreads();
    if (!tid) red[5] = rsqrtf((red[0] + red[1] + red[2] + red[3]) * (1.0f / 512.0f) + 1e-5f);
    __syncthreads();
    float rstd = red[5];
    float y0 = d0 * rstd * g[tid] + be[tid];
    float y1 = d1 * rstd * g[tid + 256] + be[tid + 256];
    _Float16 h, l;
    split_f16(y0, h, l); oh[rb + tid] = h; ol[rb + tid] = l;
    split_f16(y1, h, l); oh[rb + tid + 256] = h; ol[rb + tid + 256] = l;
    if (GATE) {
        float acc[E_];
        const float* g0 = gw + (size_t)tid * E_;
        const float* g1 = gw + (size_t)(tid + 256) * E_;
        #pragma unroll
        for (int e = 0; e < E_; ++e) acc[e] = y0 * g0[e] + y1 * g1[e];
        #pragma unroll
        for (int e = 0; e < E_; ++e)
            for (int off = 32; off; off >>= 1) acc[e] += __shfl_down(acc[e], off);
        if (!lane) {
            #pragma unroll
            for (int e = 0; e < E_; ++e) gred[wid][e] = acc[e];
        }
        __syncthreads();
        if (tid < E_)
            lg[(size_t)row * E_ + tid] = gred[0][tid] + gred[1][tid] + gred[2][tid] + gred[3][tid] + gb[tid];
    }
}

// ---------------------------------------------------------------- MoE combine + residual + LN fused
__global__ __launch_bounds__(256) void ln_add_moe(const _Float16* __restrict__ xh,
                                                  const _Float16* __restrict__ xl,
                                                  const float* __restrict__ eo,
                                                  const float* __restrict__ topv,
                                                  const int* __restrict__ route_row,
                                                  const float* __restrict__ g,
                                                  const float* __restrict__ be,
                                                  _Float16* __restrict__ oh,
                                                  _Float16* __restrict__ ol)
{
    int row = blockIdx.x;
    int r0 = route_row[row * 2], r1 = route_row[row * 2 + 1];
    float w0 = topv[row * 2], w1 = topv[row * 2 + 1];
    size_t rb = (size_t)row * D_;
    const float* e0 = eo + (size_t)r0 * D_;
    const float* e1 = eo + (size_t)r1 * D_;
    int tid = threadIdx.x;
    float v0 = (float)xh[rb + tid] + (float)xl[rb + tid] + w0 * e0[tid] + w1 * e1[tid];
    float v1 = (float)xh[rb + tid + 256] + (float)xl[rb + tid + 256] + w0 * e0[tid + 256] + w1 * e1[tid + 256];
    float s = v0 + v1;
    for (int off = 32; off; off >>= 1) s += __shfl_down(s, off);
    __shared__ float red[8];
    int lane = tid & 63, wid = tid >> 6;
    if (!lane) red[wid] = s;
    __syncthreads();
    if (!tid) red[4] = (red[0] + red[1] + red[2] + red[3]) * (1.0f / 512.0f);
    __syncthreads();
    float m = red[4];
    float d0 = v0 - m, d1 = v1 - m;
    s = d0 * d0 + d1 * d1;
    for (int off = 32; off; off >>= 1) s += __shfl_down(s, off);
    if (!lane) red[wid] = s;
    __syncthreads();
    if (!tid) red[5] = rsqrtf((red[0] + red[1] + red[2] + red[3]) * (1.0f / 512.0f) + 1e-5f);
    __syncthreads();
    float rstd = red[5];
    float y0 = d0 * rstd * g[tid] + be[tid];
    float y1 = d1 * rstd * g[tid + 256] + be[tid + 256];
    _Float16 h, l;
    split_f16(y0, h, l); oh[rb + tid] = h; ol[rb + tid] = l;
    split_f16(y1, h, l); oh[rb + tid + 256] = h; ol[rb + tid + 256] = l;
}

// ---------------------------------------------------------------- fused top2 + deterministic routing (128-granular)
// parallel 2-level prefix over 256 chunks
__global__ __launch_bounds__(1024) void gate_top2_routes(const float* __restrict__ lg,
                                                         float* __restrict__ topv,
                                                         int* __restrict__ route_tok,
                                                         int* __restrict__ route_row,
                                                         int* __restrict__ counts,
                                                         int* __restrict__ pad_base,
                                                         int* __restrict__ rb_expert)
{
    __shared__ int eid[NTOK * 2];
    __shared__ unsigned short chist[256][8];
    __shared__ unsigned short segb[8][16];
    __shared__ int pb[E_ + 1];
    __shared__ int cnt[E_];
    int t = threadIdx.x;
    #pragma unroll
    for (int s2 = 0; s2 < 2; ++s2) {
        int n = t * 2 + s2;
        float l0[E_], p[E_];
        float m = -1e30f;
        #pragma unroll
        for (int e = 0; e < E_; ++e) { l0[e] = lg[n * E_ + e]; m = fmaxf(m, l0[e]); }
        float su = 0.f;
        #pragma unroll
        for (int e = 0; e < E_; ++e) { p[e] = expf(l0[e] - m); su += p[e]; }
        float inv = 1.0f / su;
        int i1 = 0; float v1 = p[0];
        #pragma unroll
        for (int e = 1; e < E_; ++e) if (p[e] > v1) { v1 = p[e]; i1 = e; }
        int i2 = -1; float v2 = -1.f;
        #pragma unroll
        for (int e = 0; e < E_; ++e) if (e != i1 && p[e] > v2) { v2 = p[e]; i2 = e; }
        topv[n * 2] = v1 * inv; topv[n * 2 + 1] = v2 * inv;
        eid[n * 2] = i1; eid[n * 2 + 1] = i2;
    }
    #pragma unroll
    for (int g = 0; g < 5; ++g) route_tok[t + 1024 * g] = 0;
    __syncthreads();

    if (t < 256) {
        int r[16];
        #pragma unroll
        for (int i = 0; i < 16; ++i) r[i] = eid[t * 16 + i];
        #pragma unroll
        for (int e = 0; e < 8; ++e) {
            int h = 0;
            #pragma unroll
            for (int i = 0; i < 16; ++i) h += (r[i] == e) ? 1 : 0;
            chist[t][e] = (unsigned short)h;
        }
    }
    __syncthreads();

    if (t < 128) {                       // level-1: 16-chunk segment sums
        int e = t >> 4, seg = t & 15;
        int s = 0;
        #pragma unroll
        for (int i = 0; i < 16; ++i) s += chist[seg * 16 + i][e];
        segb[e][seg] = (unsigned short)s;
    }
    __syncthreads();
    if (t < 8) {                         // level-2: prefix over 16 segments
        int run = 0;
        #pragma unroll
        for (int sg = 0; sg < 16; ++sg) {
            int v = segb[t][sg];
            segb[t][sg] = (unsigned short)run;
            run += v;
        }
        cnt[t] = run;
        counts[t] = run;
    }
    __syncthreads();
    if (t < 128) {                       // level-1 writeback: prefix within segment
        int e = t >> 4, seg = t & 15;
        int run = segb[e][seg];
        #pragma unroll
        for (int i = 0; i < 16; ++i) {
            int c = seg * 16 + i;
            int v = chist[c][e];
            chist[c][e] = (unsigned short)run;
            run += v;
        }
    }
    __syncthreads();

    if (t == 0) {
        int pad = 0;
        for (int e = 0; e < 8; ++e) {
            pb[e] = pad;
            pad_base[e] = pad;
            int nb = (cnt[e] + 127) >> 7;
            for (int rb = 0; rb < nb; ++rb) rb_expert[(pad >> 7) + rb] = e;
            pad += nb << 7;
        }
        pb[8] = pad;
        pad_base[8] = pad;
    }
    __syncthreads();

    if (t < 256) {
        int r[16];
        #pragma unroll
        for (int i = 0; i < 16; ++i) r[i] = eid[t * 16 + i];
        #pragma unroll
        for (int e = 0; e < 8; ++e) {
            int o = pb[e] + chist[t][e];
            #pragma unroll
            for (int i = 0; i < 16; ++i) {
                if (r[i] == e) {
                    int slot = t * 16 + i;
                    route_tok[o] = slot >> 1;
                    route_row[slot] = o;
                    o++;
                }
            }
        }
    }
}

// ================================================================ host orchestration
extern "C" void kernel_launch(void* const* d_in, const int* in_sizes, int n_in,
                              void* d_out, int out_size, void* d_ws, size_t ws_size,
                              hipStream_t stream)
{
    const int*   src        = (const int*)  d_in[0];
    const int*   tgt        = (const int*)  d_in[1];
    const float* enc_emb    = (const float*)d_in[2];
    const float* dec_emb    = (const float*)d_in[3];
    const float* enc_attn_w = (const float*)d_in[4];
    const float* enc_attn_b = (const float*)d_in[5];
    const float* enc_ln_g   = (const float*)d_in[6];
    const float* enc_ln_b   = (const float*)d_in[7];
    const float* enc_gate_w = (const float*)d_in[8];
    const float* enc_gate_b = (const float*)d_in[9];
    const float* enc_w1     = (const float*)d_in[10];
    const float* enc_b1     = (const float*)d_in[11];
    const float* enc_w2     = (const float*)d_in[12];
    const float* enc_b2     = (const float*)d_in[13];
    const float* dec_sa_w   = (const float*)d_in[14];
    const float* dec_sa_b   = (const float*)d_in[15];
    const float* dec_ca_w   = (const float*)d_in[16];
    const float* dec_ca_b   = (const float*)d_in[17];
    const float* dec_ln_g   = (const float*)d_in[18];
    const float* dec_ln_b   = (const float*)d_in[19];
    const float* dec_gate_w = (const float*)d_in[20];
    const float* dec_gate_b = (const float*)d_in[21];
    const float* dec_w1     = (const float*)d_in[22];
    const float* dec_b1     = (const float*)d_in[23];
    const float* dec_w2     = (const float*)d_in[24];
    const float* dec_b2     = (const float*)d_in[25];
    const float* out_w      = (const float*)d_in[26];
    const float* out_b      = (const float*)d_in[27];
    float* out = (float*)d_out;

    // ---- d_out scratch (dead until final GEMM overwrites all of it)
    char* ob = (char*)d_out;
    size_t oc = 0;
    auto dalloc = [&](size_t bytes) { char* p = ob + oc; oc += (bytes + 255) & ~(size_t)255; return p; };
    _Float16* qkv_h  = (_Float16*)dalloc((size_t)NTOK * QLD * 2);
    _Float16* qkv_l  = (_Float16*)dalloc((size_t)NTOK * QLD * 2);
    _Float16* vt_h   = (_Float16*)dalloc((size_t)16 * 64 * 1024 * 2);
    _Float16* vt_l   = (_Float16*)dalloc((size_t)16 * 64 * 1024 * 2);
    float* aout  = (float*)dalloc((size_t)NTOK * D_ * 4);
    _Float16* ctx_h = (_Float16*)dalloc((size_t)NTOK * D_ * 2);
    _Float16* ctx_l = (_Float16*)dalloc((size_t)NTOK * D_ * 2);
    _Float16* encA_h = (_Float16*)dalloc((size_t)L_ * 4 * D_ * D_ * 2);
    _Float16* encA_l = (_Float16*)dalloc((size_t)L_ * 4 * D_ * D_ * 2);
    _Float16* saA_h  = (_Float16*)dalloc((size_t)L_ * 4 * D_ * D_ * 2);
    _Float16* saA_l  = (_Float16*)dalloc((size_t)L_ * 4 * D_ * D_ * 2);
    _Float16* caA_h  = (_Float16*)dalloc((size_t)L_ * 4 * D_ * D_ * 2);
    _Float16* caA_l  = (_Float16*)dalloc((size_t)L_ * 4 * D_ * D_ * 2);
    _Float16* xA_h = (_Float16*)dalloc((size_t)NTOK * D_ * 2);
    _Float16* xA_l = (_Float16*)dalloc((size_t)NTOK * D_ * 2);
    _Float16* xB_h = (_Float16*)dalloc((size_t)NTOK * D_ * 2);
    _Float16* xB_l = (_Float16*)dalloc((size_t)NTOK * D_ * 2);
    _Float16* yA_h = (_Float16*)dalloc((size_t)NTOK * D_ * 2);
    _Float16* yA_l = (_Float16*)dalloc((size_t)NTOK * D_ * 2);
    _Float16* yB_h = (_Float16*)dalloc((size_t)NTOK * D_ * 2);
    _Float16* yB_l = (_Float16*)dalloc((size_t)NTOK * D_ * 2);

    // ---- ws scratch (~360 MB of ~1 GB)
    char* wp = (char*)d_ws;
    size_t wc = 0;
    auto walloc = [&](size_t bytes) { char* p = wp + wc; wc += (bytes + 255) & ~(size_t)255; return p; };
    _Float16* outwT_h = (_Float16*)walloc((size_t)V_ * D_ * 2);
    _Float16* final_h = (_Float16*)walloc((size_t)NTOK * D_ * 2);
    size_t wsz = (size_t)L_ * E_ * D_ * F_;
    _Float16* ew1t_h = (_Float16*)walloc(wsz * 2);
    _Float16* ew1t_l = (_Float16*)walloc(wsz * 2);
    _Float16* ew2t_h = (_Float16*)walloc(wsz * 2);
    _Float16* ew2t_l = (_Float16*)walloc(wsz * 2);
    _Float16* dw1t_h = (_Float16*)walloc(wsz * 2);
    _Float16* dw1t_l = (_Float16*)walloc(wsz * 2);
    _Float16* dw2t_h = (_Float16*)walloc(wsz * 2);
    _Float16* dw2t_l = (_Float16*)walloc(wsz * 2);
    _Float16* hbuf_h  = (_Float16*)walloc((size_t)MAXPAD * F_ * 2);
    _Float16* hbuf_l  = (_Float16*)walloc((size_t)MAXPAD * F_ * 2);
    float*    eobuf   = (float*)walloc((size_t)MAXPAD * D_ * 4);
    float* lg   = (float*)walloc((size_t)NTOK * E_ * 4);
    float* topv = (float*)walloc((size_t)NTOK * 2 * 4);
    int*   route_tok = (int*)walloc((size_t)MAXPAD * 4);
    int*   route_row = (int*)walloc((size_t)NTOK * 2 * 4);
    int*   counts    = (int*)walloc(64);
    int*   pad_base  = (int*)walloc(64);
    int*   rb_expert = (int*)walloc((size_t)128 * 4);

    // ---- all weight transposes upfront
    transpose_w3<<<dim3(8, 8, 24), 256, 0, stream>>>(
        enc_attn_w, encA_h, encA_l, dec_sa_w, saA_h, saA_l, dec_ca_w, caA_h, caA_l);
    transpose_w<false><<<dim3(500, 8, 1), 256, 0, stream>>>(out_w, outwT_h, nullptr, D_, V_);
    transpose_w<true><<<dim3(32, 8, L_ * E_), 256, 0, stream>>>(enc_w1, ew1t_h, ew1t_l, D_, F_);
    transpose_w<true><<<dim3(8, 32, L_ * E_), 256, 0, stream>>>(enc_w2, ew2t_h, ew2t_l, F_, D_);
    transpose_w<true><<<dim3(32, 8, L_ * E_), 256, 0, stream>>>(dec_w1, dw1t_h, dw1t_l, D_, F_);
    transpose_w<true><<<dim3(8, 32, L_ * E_), 256, 0, stream>>>(dec_w2, dw2t_h, dw2t_l, F_, D_);

    auto run_mha = [&](const _Float16* q_h, const _Float16* q_l,
                       const _Float16* kv_h, const _Float16* kv_l,
                       const _Float16* wT_h, const _Float16* wT_l, const float* bt,
                       const int* ktoks, int causal, bool fused) {
        if (fused) {
            gemm_mfma<0, false, 2, 3, 64, 128, false><<<dim3(32, 12), 256, 0, stream>>>(
                q_h, q_l, wT_h, wT_l, bt, nullptr, qkv_h, qkv_l, vt_h, vt_l, 0,
                NTOK, D_, 1536, QLD, nullptr, nullptr, nullptr, nullptr);
        } else {
            gemm_mfma<0, false, 1, 3, 64, 64, false><<<dim3(32, 8), 256, 0, stream>>>(
                q_h, q_l, wT_h, wT_l, bt, nullptr, qkv_h, qkv_l, nullptr, nullptr, 0,
                NTOK, D_, 512, QLD, nullptr, nullptr, nullptr, nullptr);
            gemm_mfma<0, false, 2, 3, 64, 128, false><<<dim3(32, 8), 256, 0, stream>>>(
                kv_h, kv_l, wT_h + (size_t)D_ * D_, wT_l + (size_t)D_ * D_, bt + D_,
                nullptr, qkv_h, qkv_l, vt_h, vt_l, 512,
                NTOK, D_, 1024, QLD, nullptr, nullptr, nullptr, nullptr);
        }
        if (causal)
            attn_flash<1><<<dim3(16, 16), 512, 0, stream>>>(qkv_h, qkv_l, vt_h, vt_l, ktoks, ctx_h, ctx_l);
        else
            attn_flash<0><<<dim3(16, 16), 512, 0, stream>>>(qkv_h, qkv_l, vt_h, vt_l, ktoks, ctx_h, ctx_l);
        gemm_mfma<0, false, 0, 3, 64, 64, false><<<dim3(32, 8), 256, 0, stream>>>(
            ctx_h, ctx_l, wT_h + (size_t)3 * D_ * D_, wT_l + (size_t)3 * D_ * D_,
            bt + 3 * D_, aout, nullptr, nullptr, nullptr, nullptr, 0,
            NTOK, D_, 512, 512, nullptr, nullptr, nullptr, nullptr);
    };

    auto run_moe = [&](const _Float16* x_h, const _Float16* x_l,
                       const _Float16* w1h, const _Float16* w1l,
                       const _Float16* w2h, const _Float16* w2l,
                       const float* b1p, const float* b2p, bool p3) {
        gate_top2_routes<<<1, 1024, 0, stream>>>(lg, topv, route_tok, route_row, counts, pad_base, rb_expert);
        if (p3) {
            gemm_mfma<1, true, 1, 3, 128, 128, false><<<dim3(RBLK, 16), 256, 0, stream>>>(
                x_h, x_l, w1h, w1l, b1p, nullptr, hbuf_h, hbuf_l, nullptr, nullptr, 0,
                0, D_, F_, F_, route_tok, rb_expert, pad_base, counts);
            gemm_mfma<2, false, 0, 3, 128, 64, false><<<dim3(RBLK, 8), 256, 0, stream>>>(
                hbuf_h, hbuf_l, w2h, w2l, b2p, eobuf, nullptr, nullptr, nullptr, nullptr, 0,
                0, F_, D_, D_, route_tok, rb_expert, pad_base, counts);
        } else {
            gemm_mfma<1, true, 1, 1, 128, 128, false><<<dim3(RBLK, 16), 256, 0, stream>>>(
                x_h, nullptr, w1h, nullptr, b1p, nullptr, hbuf_h, hbuf_l, nullptr, nullptr, 0,
                0, D_, F_, F_, route_tok, rb_expert, pad_base, counts);
            gemm_mfma<2, false, 0, 1, 128, 64, false><<<dim3(RBLK, 8), 256, 0, stream>>>(
                hbuf_h, nullptr, w2h, nullptr, b2p, eobuf, nullptr, nullptr, nullptr, nullptr, 0,
                0, F_, D_, D_, route_tok, rb_expert, pad_base, counts);
        }
    };

    // ---------------- encoder ----------------
    embed_pe<<<B_ * S_, 256, 0, stream>>>(src, enc_emb, xA_h, xA_l, S_);
    _Float16* cur_h = xA_h; _Float16* cur_l = xA_l;
    _Float16* alt_h = xB_h; _Float16* alt_l = xB_l;
    for (int l = 0; l < L_; ++l) {
        run_mha(cur_h, cur_l, nullptr, nullptr,
                encA_h + (size_t)l * 4 * D_ * D_, encA_l + (size_t)l * 4 * D_ * D_,
                enc_attn_b + (size_t)l * 4 * D_, src, 0, true);
        ln_add<true><<<NTOK, 256, 0, stream>>>(cur_h, cur_l, aout,
            enc_ln_g + (size_t)(l * 2 + 0) * D_, enc_ln_b + (size_t)(l * 2 + 0) * D_,
            alt_h, alt_l, enc_gate_w + (size_t)l * D_ * E_, enc_gate_b + (size_t)l * E_, lg);
        { _Float16* t = cur_h; cur_h = alt_h; alt_h = t; t = cur_l; cur_l = alt_l; alt_l = t; }
        run_moe(cur_h, cur_l,
                ew1t_h + (size_t)l * E_ * D_ * F_, ew1t_l + (size_t)l * E_ * D_ * F_,
                ew2t_h + (size_t)l * E_ * D_ * F_, ew2t_l + (size_t)l * E_ * D_ * F_,
                enc_b1 + (size_t)l * E_ * F_, enc_b2 + (size_t)l * E_ * D_, true);
        ln_add_moe<<<NTOK, 256, 0, stream>>>(cur_h, cur_l, eobuf, topv, route_row,
            enc_ln_g + (size_t)(l * 2 + 1) * D_, enc_ln_b + (size_t)(l * 2 + 1) * D_,
            alt_h, alt_l);
        { _Float16* t = cur_h; cur_h = alt_h; alt_h = t; t = cur_l; cur_l = alt_l; alt_l = t; }
    }
    _Float16* enc_h = cur_h; _Float16* enc_l = cur_l;

    // ---------------- decoder ----------------
    embed_pe<<<B_ * T_, 256, 0, stream>>>(tgt, dec_emb, yA_h, yA_l, T_);
    _Float16* dc_h = yA_h; _Float16* dc_l = yA_l;
    _Float16* da_h = yB_h; _Float16* da_l = yB_l;
    for (int l = 0; l < L_; ++l) {
        run_mha(dc_h, dc_l, nullptr, nullptr,
                saA_h + (size_t)l * 4 * D_ * D_, saA_l + (size_t)l * 4 * D_ * D_,
                dec_sa_b + (size_t)l * 4 * D_, tgt, 1, true);
        ln_add<false><<<NTOK, 256, 0, stream>>>(dc_h, dc_l, aout,
            dec_ln_g + (size_t)(l * 3 + 0) * D_, dec_ln_b + (size_t)(l * 3 + 0) * D_,
            da_h, da_l, nullptr, nullptr, nullptr);
        { _Float16* t = dc_h; dc_h = da_h; da_h = t; t = dc_l; dc_l = da_l; da_l = t; }
        run_mha(dc_h, dc_l, enc_h, enc_l,
                caA_h + (size_t)l * 4 * D_ * D_, caA_l + (size_t)l * 4 * D_ * D_,
                dec_ca_b + (size_t)l * 4 * D_, src, 0, false);
        ln_add<true><<<NTOK, 256, 0, stream>>>(dc_h, dc_l, aout,
            dec_ln_g + (size_t)(l * 3 + 1) * D_, dec_ln_b + (size_t)(l * 3 + 1) * D_,
            da_h, da_l, dec_gate_w + (size_t)l * D_ * E_, dec_gate_b + (size_t)l * E_, lg);
        { _Float16* t = dc_h; dc_h = da_h; da_h = t; t = dc_l; dc_l = da_l; da_l = t; }
        bool last = (l == L_ - 1);
        run_moe(dc_h, dc_l,
                dw1t_h + (size_t)l * E_ * D_ * F_, dw1t_l + (size_t)l * E_ * D_ * F_,
                dw2t_h + (size_t)l * E_ * D_ * F_, dw2t_l + (size_t)l * E_ * D_ * F_,
                dec_b1 + (size_t)l * E_ * F_, dec_b2 + (size_t)l * E_ * D_, !last);
        ln_add_moe<<<NTOK, 256, 0, stream>>>(dc_h, dc_l, eobuf, topv, route_row,
            dec_ln_g + (size_t)(l * 3 + 2) * D_, dec_ln_b + (size_t)(l * 3 + 2) * D_,
            last ? final_h : da_h, da_l);
        { _Float16* t = dc_h; dc_h = da_h; da_h = t; t = dc_l; dc_l = da_l; da_l = t; }
    }

    // ---------------- final projection (single-pass f16 MFMA, XCD-swizzled; overwrites all of d_out)
    gemm_mfma<0, false, 0, 1, 128, 128, true><<<dim3(NTOK / 128, V_ / 128), 256, 0, stream>>>(
        final_h, nullptr, outwT_h, nullptr, out_b, out, nullptr, nullptr, nullptr, nullptr, 0,
        NTOK, D_, V_, V_, nullptr, nullptr, nullptr, nullptr);
}

// Round 10
// 1198.038 us; speedup vs baseline: 1.0442x; 1.0442x over previous
//
#include <hip/hip_runtime.h>
#include <hip/hip_bf16.h>

#define L_ 2
#define D_ 512
#define H_ 8
#define DK_ 64
#define F_ 2048
#define E_ 8
#define V_ 32000
#define B_ 2
#define S_ 1024
#define T_ 1024
#define NTOK (B_*S_)
#define MAXPAD 4608            // per-expert 64-padded total upper bound
#define RB64   72              // MAXPAD/64
#define QLD 1536

typedef unsigned short u16;
typedef _Float16 f16x8 __attribute__((ext_vector_type(8)));
typedef _Float16 f16x4 __attribute__((ext_vector_type(4)));
typedef float f32x4 __attribute__((ext_vector_type(4)));

__device__ __forceinline__ void gload16(const void* g, const void* l) {
    __builtin_amdgcn_global_load_lds(
        (const __attribute__((address_space(1))) void*)g,
        (__attribute__((address_space(3))) void*)l, 16, 0, 0);
}

__device__ __forceinline__ void split_f16(float v, _Float16& h, _Float16& l) {
    h = (_Float16)v;
    l = (_Float16)(v - (float)h);
}

// ---------------------------------------------------------------- embedding + PE (hi/lo f16 only)
__global__ __launch_bounds__(256) void embed_pe(const int* __restrict__ toks,
                                                const float* __restrict__ emb,
                                                _Float16* __restrict__ oh,
                                                _Float16* __restrict__ ol, int Slen)
{
    int n = blockIdx.x;
    int spos = n % Slen;
    int tok = toks[n];
    const float* erow = emb + (size_t)tok * D_;
    size_t rb = (size_t)n * D_;
    for (int j = threadIdx.x; j < D_; j += 256) {
        int i = j >> 1;
        float arg = (float)spos * expf(-(float)i * 0.035977892f);
        float pe = (j & 1) ? cosf(arg) : sinf(arg);
        float v = erow[j] + pe;
        _Float16 h, l; split_f16(v, h, l);
        oh[rb + j] = h; ol[rb + j] = l;
    }
}

// ---------------------------------------------------------------- weight transpose f32[R][C] -> f16 hi/lo [C][R]
template<bool WLO>
__global__ __launch_bounds__(256) void transpose_w(const float* __restrict__ in,
                                                   _Float16* __restrict__ oh,
                                                   _Float16* __restrict__ ol, int R, int C)
{
    __shared__ float t[64][65];
    size_t sb = (size_t)blockIdx.z * R * C;
    in += sb; oh += sb; if (WLO) ol += sb;
    int c0 = blockIdx.x * 64, r0 = blockIdx.y * 64;
    int tid = threadIdx.x;
    {
        int r = tid >> 4;
        int cq = (tid & 15) * 4;
        #pragma unroll
        for (int p = 0; p < 4; ++p) {
            int rr = r + p * 16;
            float4 v = *(const float4*)&in[(size_t)(r0 + rr) * C + c0 + cq];
            t[rr][cq] = v.x; t[rr][cq + 1] = v.y; t[rr][cq + 2] = v.z; t[rr][cq + 3] = v.w;
        }
    }
    __syncthreads();
    int rp = (tid & 15) * 4;
    int cb = tid >> 4;
    #pragma unroll
    for (int p = 0; p < 4; ++p) {
        int c = cb + p * 16;
        f16x4 hv, lv;
        #pragma unroll
        for (int j = 0; j < 4; ++j) {
            float v = t[rp + j][c];
            _Float16 h = (_Float16)v;
            hv[j] = h;
            if (WLO) lv[j] = (_Float16)(v - (float)h);
        }
        *(f16x4*)&oh[(size_t)(c0 + c) * R + r0 + rp] = hv;
        if (WLO) *(f16x4*)&ol[(size_t)(c0 + c) * R + r0 + rp] = lv;
    }
}

// 3 attn-weight sets (D x D, 8 matrices each) in one launch; z: set = z>>3, sub = z&7
__global__ __launch_bounds__(256) void transpose_w3(
    const float* __restrict__ i0, _Float16* __restrict__ h0, _Float16* __restrict__ l0,
    const float* __restrict__ i1, _Float16* __restrict__ h1, _Float16* __restrict__ l1,
    const float* __restrict__ i2, _Float16* __restrict__ h2, _Float16* __restrict__ l2)
{
    __shared__ float t[64][65];
    int set = blockIdx.z >> 3, sub = blockIdx.z & 7;
    const float* in = (set == 0) ? i0 : (set == 1) ? i1 : i2;
    _Float16* oh = (set == 0) ? h0 : (set == 1) ? h1 : h2;
    _Float16* ol = (set == 0) ? l0 : (set == 1) ? l1 : l2;
    size_t sb = (size_t)sub * D_ * D_;
    in += sb; oh += sb; ol += sb;
    int c0 = blockIdx.x * 64, r0 = blockIdx.y * 64;
    int tid = threadIdx.x;
    {
        int r = tid >> 4;
        int cq = (tid & 15) * 4;
        #pragma unroll
        for (int p = 0; p < 4; ++p) {
            int rr = r + p * 16;
            float4 v = *(const float4*)&in[(size_t)(r0 + rr) * D_ + c0 + cq];
            t[rr][cq] = v.x; t[rr][cq + 1] = v.y; t[rr][cq + 2] = v.z; t[rr][cq + 3] = v.w;
        }
    }
    __syncthreads();
    int rp = (tid & 15) * 4;
    int cb = tid >> 4;
    #pragma unroll
    for (int p = 0; p < 4; ++p) {
        int c = cb + p * 16;
        f16x4 hv, lv;
        #pragma unroll
        for (int j = 0; j < 4; ++j) {
            float v = t[rp + j][c];
            _Float16 h = (_Float16)v;
            hv[j] = h;
            lv[j] = (_Float16)(v - (float)h);
        }
        *(f16x4*)&oh[(size_t)(c0 + c) * D_ + r0 + rp] = hv;
        *(f16x4*)&ol[(size_t)(c0 + c) * D_ + r0 + rp] = lv;
    }
}

// ---------------------------------------------------------------- MFMA GEMM (tile-templated)
template<int MODE, bool RELU, int OUTMODE, int PASSES, int TM, int TN>
__global__ __launch_bounds__(256, 2) void gemm_mfma(
    const _Float16* __restrict__ Ah, const _Float16* __restrict__ Al,
    const _Float16* __restrict__ Wh, const _Float16* __restrict__ Wl,
    const float* __restrict__ biasbase,
    float* __restrict__ Cf, _Float16* __restrict__ Ch, _Float16* __restrict__ Cl,
    _Float16* __restrict__ vt_h, _Float16* __restrict__ vt_l, int cbase,
    int M, int Kd, int N, int ldc,
    const int* __restrict__ route_tok, const int* __restrict__ rb_expert,
    const int* __restrict__ pad_base, const int* __restrict__ counts)
{
    constexpr int AR = TM / 32;
    constexpr int BR = TN / 32;
    int row0 = blockIdx.x * TM;
    const _Float16* Wmh = Wh;
    const _Float16* Wml = Wl;
    const float* bias = biasbase;
    int vend = M;
    if (MODE != 0) {
        int total = pad_base[E_];
        if (row0 >= total) return;
        int e = rb_expert[row0 >> 6];
        vend = pad_base[e] + counts[e];
        Wmh = Wh + (size_t)e * Kd * N;
        if (PASSES == 3) Wml = Wl + (size_t)e * Kd * N;
        bias = biasbase + (size_t)e * N;
    }
    int col0 = blockIdx.y * TN;
    int tid = threadIdx.x;
    int lane = tid & 63, w = tid >> 6;
    int wm = w >> 1, wn = w & 1;

    __shared__ _Float16 lds[(PASSES == 3 ? 2 : 1) * (TM + TN) * 64];
    _Float16* lAh = lds;
    _Float16* lBh = lds + TM * 64;
    _Float16* lAl = (PASSES == 3) ? lds + (TM + TN) * 64 : nullptr;
    _Float16* lBl = (PASSES == 3) ? lds + (TM + TN) * 64 + TM * 64 : nullptr;

    int srow8 = lane >> 3;
    int q8 = lane & 7;
    size_t aoff[AR], boff[BR];
    #pragma unroll
    for (int j = 0; j < AR; ++j) {
        int m = w * (TM / 4) + j * 8 + srow8;
        int gr = row0 + m;
        int ar = (MODE == 1) ? route_tok[gr] : gr;
        int ss = (q8 ^ (m & 7)) << 3;
        aoff[j] = (size_t)ar * Kd + ss;
    }
    #pragma unroll
    for (int j = 0; j < BR; ++j) {
        int m = w * (TN / 4) + j * 8 + srow8;
        int ss = (q8 ^ (m & 7)) << 3;
        boff[j] = (size_t)(col0 + m) * Kd + ss;
    }

    f32x4 zero4 = {0.f, 0.f, 0.f, 0.f};
    f32x4 acc[AR][BR];
    #pragma unroll
    for (int i = 0; i < AR; ++i)
        #pragma unroll
        for (int j = 0; j < BR; ++j) acc[i][j] = zero4;

    int lm = lane & 15, kg = lane >> 4;

    for (int k0 = 0; k0 < Kd; k0 += 64) {
        #pragma unroll
        for (int j = 0; j < AR; ++j) {
            int lb = (w * (TM / 4) + j * 8) * 64;
            gload16(Ah + aoff[j] + k0, lAh + lb);
            if (PASSES == 3) gload16(Al + aoff[j] + k0, lAl + lb);
        }
        #pragma unroll
        for (int j = 0; j < BR; ++j) {
            int lb = (w * (TN / 4) + j * 8) * 64;
            gload16(Wmh + boff[j] + k0, lBh + lb);
            if (PASSES == 3) gload16(Wml + boff[j] + k0, lBl + lb);
        }
        __syncthreads();
        #pragma unroll
        for (int ks = 0; ks < 2; ++ks) {
            f16x8 ah[AR], bh[BR];
            #pragma unroll
            for (int i = 0; i < AR; ++i) {
                int m = wm * (TM / 2) + i * 16 + lm;
                ah[i] = *(const f16x8*)&lAh[m * 64 + ((((ks << 2) + kg) ^ (m & 7)) << 3)];
            }
            #pragma unroll
            for (int j = 0; j < BR; ++j) {
                int n = wn * (TN / 2) + j * 16 + lm;
                bh[j] = *(const f16x8*)&lBh[n * 64 + ((((ks << 2) + kg) ^ (n & 7)) << 3)];
            }
            #pragma unroll
            for (int i = 0; i < AR; ++i)
                #pragma unroll
                for (int jn = 0; jn < BR; ++jn)
                    acc[i][jn] = __builtin_amdgcn_mfma_f32_16x16x32_f16(ah[i], bh[jn], acc[i][jn], 0, 0, 0);
            if (PASSES == 3) {
                f16x8 bl[BR];
                #pragma unroll
                for (int j = 0; j < BR; ++j) {
                    int n = wn * (TN / 2) + j * 16 + lm;
                    bl[j] = *(const f16x8*)&lBl[n * 64 + ((((ks << 2) + kg) ^ (n & 7)) << 3)];
                }
                #pragma unroll
                for (int i = 0; i < AR; ++i)
                    #pragma unroll
                    for (int jn = 0; jn < BR; ++jn)
                        acc[i][jn] = __builtin_amdgcn_mfma_f32_16x16x32_f16(ah[i], bl[jn], acc[i][jn], 0, 0, 0);
                f16x8 al[AR];
                #pragma unroll
                for (int i = 0; i < AR; ++i) {
                    int m = wm * (TM / 2) + i * 16 + lm;
                    al[i] = *(const f16x8*)&lAl[m * 64 + ((((ks << 2) + kg) ^ (m & 7)) << 3)];
                }
                #pragma unroll
                for (int i = 0; i < AR; ++i)
                    #pragma unroll
                    for (int jn = 0; jn < BR; ++jn)
                        acc[i][jn] = __builtin_amdgcn_mfma_f32_16x16x32_f16(al[i], bh[jn], acc[i][jn], 0, 0, 0);
            }
        }
        __syncthreads();
    }

    float bv[BR];
    #pragma unroll
    for (int jn = 0; jn < BR; ++jn) bv[jn] = bias[col0 + wn * (TN / 2) + jn * 16 + lm];
    int rowb = row0 + wm * (TM / 2) + (lane >> 4) * 4;

    if (OUTMODE == 2 && (col0 + cbase) >= 1024) {
        #pragma unroll
        for (int i = 0; i < AR; ++i) {
            int row = rowb + i * 16;
            int b = row >> 10, q = row & 1023;
            #pragma unroll
            for (int jn = 0; jn < BR; ++jn) {
                int vcol = col0 + cbase - 1024 + wn * (TN / 2) + jn * 16 + lm;
                int hh = vcol >> 6, dd = vcol & 63;
                f16x4 hv, lv;
                #pragma unroll
                for (int r = 0; r < 4; ++r) {
                    float v = acc[i][jn][r] + bv[jn];
                    _Float16 x1, x2; split_f16(v, x1, x2);
                    hv[r] = x1; lv[r] = x2;
                }
                size_t vtoff = ((size_t)((b << 3) + hh) * 64 + dd) * 1024 + q;
                *(f16x4*)&vt_h[vtoff] = hv;
                *(f16x4*)&vt_l[vtoff] = lv;
            }
        }
        return;
    }

    #pragma unroll
    for (int i = 0; i < AR; ++i) {
        #pragma unroll
        for (int r = 0; r < 4; ++r) {
            int row = rowb + i * 16 + r;
            if (MODE != 0 && row >= vend) continue;
            #pragma unroll
            for (int jn = 0; jn < BR; ++jn) {
                float v = acc[i][jn][r] + bv[jn];
                if (RELU) v = fmaxf(v, 0.f);
                int c = col0 + wn * (TN / 2) + jn * 16 + lm;
                if (OUTMODE == 0) {
                    Cf[(size_t)row * ldc + c] = v;
                } else {
                    _Float16 h, l; split_f16(v, h, l);
                    Ch[(size_t)row * ldc + cbase + c] = h;
                    Cl[(size_t)row * ldc + cbase + c] = l;
                }
            }
        }
    }
}

// ---------------------------------------------------------------- flash attention, 8-wave split-K
template<int CAUSAL>
__global__ __launch_bounds__(512, 1) void attn_flash(
    const _Float16* __restrict__ qkvh, const _Float16* __restrict__ qkvl,
    const _Float16* __restrict__ vth, const _Float16* __restrict__ vtl,
    const int* __restrict__ ktoks,
    _Float16* __restrict__ ch, _Float16* __restrict__ cl)
{
    int q0 = blockIdx.x * 64;
    int bh = blockIdx.y, b = bh >> 3, h = bh & 7;
    int tid = threadIdx.x, lane = tid & 63, w = tid >> 6;
    int qg = w & 3, kh = w >> 2;
    int lm = lane & 15, kg = lane >> 4;
    int srow8 = lane >> 3, q8 = lane & 7;
    int tb = b * S_;

    __shared__ _Float16 smem[49152];
    _Float16* hb  = smem + kh * 16384;
    _Float16* lKh = hb;
    _Float16* lKl = hb + 4096;
    _Float16* lVh = hb + 8192;
    _Float16* lVl = hb + 12288;
    _Float16* lPh = smem + 32768 + w * 1024;
    _Float16* lPl = smem + 40960 + w * 1024;

    size_t qbase = (size_t)b * S_ * QLD + h * DK_;
    const _Float16* Qh = qkvh + qbase;
    const _Float16* Ql = qkvl + qbase;
    const _Float16* Kh = qkvh + qbase + 512;
    const _Float16* Kl = qkvl + qbase + 512;
    const _Float16* Vh = vth + (size_t)bh * 64 * 1024;
    const _Float16* Vl = vtl + (size_t)bh * 64 * 1024;

    f16x8 qfh[2], qfl[2];
    {
        int qr = q0 + qg * 16 + lm;
        #pragma unroll
        for (int ks = 0; ks < 2; ++ks) {
            qfh[ks] = *(const f16x8*)&Qh[(size_t)qr * QLD + ks * 32 + kg * 8];
            qfl[ks] = *(const f16x8*)&Ql[(size_t)qr * QLD + ks * 32 + kg * 8];
        }
    }

    float mreg[4], lreg[4];
    f32x4 od[4];
    f32x4 zero4 = {0.f, 0.f, 0.f, 0.f};
    #pragma unroll
    for (int r = 0; r < 4; ++r) { mreg[r] = -1e30f; lreg[r] = 0.f; }
    #pragma unroll
    for (int jn = 0; jn < 4; ++jn) od[jn] = zero4;

    int qrow[4];
    #pragma unroll
    for (int r = 0; r < 4; ++r) qrow[r] = q0 + qg * 16 + (lane >> 4) * 4 + r;

    int nkt = CAUSAL ? (q0 >> 6) + 1 : 16;
    int nhalf = (nkt + 1) >> 1;

    for (int it = 0; it < nhalf; ++it) {
        int kt = 2 * it + kh;
        bool active = kt < nkt;
        int k0 = kt * 64;

        if (active) {
            #pragma unroll
            for (int j = 0; j < 2; ++j) {
                int row = qg * 16 + j * 8 + srow8;
                int lb = (qg * 16 + j * 8) * 64;
                int ss = (q8 ^ (row & 7)) << 3;
                gload16(Kh + (size_t)(k0 + row) * QLD + ss, lKh + lb);
                gload16(Kl + (size_t)(k0 + row) * QLD + ss, lKl + lb);
                gload16(Vh + (size_t)row * 1024 + k0 + ss, lVh + lb);
                gload16(Vl + (size_t)row * 1024 + k0 + ss, lVl + lb);
            }
        }
        __syncthreads();

        if (active) {
            bool diag = CAUSAL && (kt == (q0 >> 6));
            f32x4 accs[4];
            #pragma unroll
            for (int jn = 0; jn < 4; ++jn) accs[jn] = zero4;
            #pragma unroll
            for (int ks = 0; ks < 2; ++ks) {
                #pragma unroll
                for (int jn = 0; jn < 4; ++jn) {
                    int n = jn * 16 + lm;
                    int koff = n * 64 + ((((ks << 2) + kg) ^ (n & 7)) << 3);
                    f16x8 bhv = *(const f16x8*)&lKh[koff];
                    f16x8 blv = *(const f16x8*)&lKl[koff];
                    accs[jn] = __builtin_amdgcn_mfma_f32_16x16x32_f16(qfh[ks], bhv, accs[jn], 0, 0, 0);
                    accs[jn] = __builtin_amdgcn_mfma_f32_16x16x32_f16(qfh[ks], blv, accs[jn], 0, 0, 0);
                    accs[jn] = __builtin_amdgcn_mfma_f32_16x16x32_f16(qfl[ks], bhv, accs[jn], 0, 0, 0);
                }
            }

            float sv[4][4];
            #pragma unroll
            for (int jn = 0; jn < 4; ++jn) {
                int kglob = k0 + jn * 16 + lm;
                bool pad_ok = (ktoks[tb + kglob] != 0);
                #pragma unroll
                for (int r = 0; r < 4; ++r) {
                    float s = accs[jn][r] * 0.125f;
                    bool keep = pad_ok && (!diag || kglob <= qrow[r]);
                    sv[jn][r] = keep ? s : -1e9f;
                }
            }
            float pv[4][4];
            #pragma unroll
            for (int r = 0; r < 4; ++r) {
                float tm = fmaxf(fmaxf(sv[0][r], sv[1][r]), fmaxf(sv[2][r], sv[3][r]));
                tm = fmaxf(tm, __shfl_xor(tm, 1));
                tm = fmaxf(tm, __shfl_xor(tm, 2));
                tm = fmaxf(tm, __shfl_xor(tm, 4));
                tm = fmaxf(tm, __shfl_xor(tm, 8));
                float mnew = fmaxf(mreg[r], tm);
                float corr = expf(mreg[r] - mnew);
                lreg[r] *= corr;
                #pragma unroll
                for (int jn = 0; jn < 4; ++jn) od[jn][r] *= corr;
                float psum = 0.f;
                #pragma unroll
                for (int jn = 0; jn < 4; ++jn) {
                    float p = expf(sv[jn][r] - mnew);
                    pv[jn][r] = p;
                    psum += p;
                }
                psum += __shfl_xor(psum, 1);
                psum += __shfl_xor(psum, 2);
                psum += __shfl_xor(psum, 4);
                psum += __shfl_xor(psum, 8);
                lreg[r] += psum;
                mreg[r] = mnew;
            }

            #pragma unroll
            for (int jn = 0; jn < 4; ++jn) {
                int col = jn * 16 + lm;
                #pragma unroll
                for (int r = 0; r < 4; ++r) {
                    int rr = (lane >> 4) * 4 + r;
                    int idx = rr * 64 + (((col >> 3) ^ (rr & 7)) << 3) + (col & 7);
                    _Float16 hh, ll; split_f16(pv[jn][r], hh, ll);
                    lPh[idx] = hh; lPl[idx] = ll;
                }
            }

            #pragma unroll
            for (int ks = 0; ks < 2; ++ks) {
                int poff = lm * 64 + ((((ks << 2) + kg) ^ (lm & 7)) << 3);
                f16x8 pah = *(const f16x8*)&lPh[poff];
                f16x8 pal = *(const f16x8*)&lPl[poff];
                #pragma unroll
                for (int jn = 0; jn < 4; ++jn) {
                    int n = jn * 16 + lm;
                    int noff = n * 64 + ((((ks << 2) + kg) ^ (n & 7)) << 3);
                    f16x8 vbh = *(const f16x8*)&lVh[noff];
                    f16x8 vbl = *(const f16x8*)&lVl[noff];
                    od[jn] = __builtin_amdgcn_mfma_f32_16x16x32_f16(pah, vbh, od[jn], 0, 0, 0);
                    od[jn] = __builtin_amdgcn_mfma_f32_16x16x32_f16(pah, vbl, od[jn], 0, 0, 0);
                    od[jn] = __builtin_amdgcn_mfma_f32_16x16x32_f16(pal, vbh, od[jn], 0, 0, 0);
                }
            }
        }
        __syncthreads();
    }

    float* mrg = (float*)(smem + 32768);
    if (kh == 1) {
        float* mp = mrg + ((size_t)qg * 64 + lane) * 24;
        #pragma unroll
        for (int jn = 0; jn < 4; ++jn)
            #pragma unroll
            for (int r = 0; r < 4; ++r) mp[jn * 4 + r] = od[jn][r];
        #pragma unroll
        for (int r = 0; r < 4; ++r) { mp[16 + r] = mreg[r]; mp[20 + r] = lreg[r]; }
    }
    __syncthreads();
    if (kh == 0) {
        float* mp = mrg + ((size_t)qg * 64 + lane) * 24;
        #pragma unroll
        for (int r = 0; r < 4; ++r) {
            float m1 = mp[16 + r], l1 = mp[20 + r];
            float m = fmaxf(mreg[r], m1);
            float c0 = expf(mreg[r] - m), c1 = expf(m1 - m);
            float inv = 1.0f / (lreg[r] * c0 + l1 * c1);
            size_t rbase = (size_t)(tb + qrow[r]) * D_ + h * DK_;
            #pragma unroll
            for (int jn = 0; jn < 4; ++jn) {
                float o = (od[jn][r] * c0 + mp[jn * 4 + r] * c1) * inv;
                _Float16 hh, ll; split_f16(o, hh, ll);
                int d = jn * 16 + lm;
                ch[rbase + d] = hh; cl[rbase + d] = ll;
            }
        }
    }
}

// ---------------------------------------------------------------- residual + LN, wave-per-row (4 rows/block)
template<bool GATE>
__global__ __launch_bounds__(256) void ln_add(const _Float16* __restrict__ xh,
                                              const _Float16* __restrict__ xl,
                                              const float* __restrict__ r,
                                              const float* __restrict__ g,
                                              const float* __restrict__ be,
                                              _Float16* __restrict__ oh,
                                              _Float16* __restrict__ ol,
                                              const float* __restrict__ gw,
                                              const float* __restrict__ gbias,
                                              float* __restrict__ lg)
{
    int w = threadIdx.x >> 6, lane = threadIdx.x & 63;
    int row = blockIdx.x * 4 + w;
    int col = lane * 8;
    size_t rb = (size_t)row * D_ + col;
    f16x8 vh = *(const f16x8*)&xh[rb];
    f16x8 vl = *(const f16x8*)&xl[rb];
    float4 ra = *(const float4*)&r[rb];
    float4 rc = *(const float4*)&r[rb + 4];
    float v[8];
    v[0] = (float)vh[0] + (float)vl[0] + ra.x;
    v[1] = (float)vh[1] + (float)vl[1] + ra.y;
    v[2] = (float)vh[2] + (float)vl[2] + ra.z;
    v[3] = (float)vh[3] + (float)vl[3] + ra.w;
    v[4] = (float)vh[4] + (float)vl[4] + rc.x;
    v[5] = (float)vh[5] + (float)vl[5] + rc.y;
    v[6] = (float)vh[6] + (float)vl[6] + rc.z;
    v[7] = (float)vh[7] + (float)vl[7] + rc.w;
    float s = 0.f;
    #pragma unroll
    for (int i = 0; i < 8; ++i) s += v[i];
    #pragma unroll
    for (int off = 32; off; off >>= 1) s += __shfl_xor(s, off);
    float m = s * (1.0f / 512.0f);
    float d[8];
    float q = 0.f;
    #pragma unroll
    for (int i = 0; i < 8; ++i) { d[i] = v[i] - m; q += d[i] * d[i]; }
    #pragma unroll
    for (int off = 32; off; off >>= 1) q += __shfl_xor(q, off);
    float rstd = rsqrtf(q * (1.0f / 512.0f) + 1e-5f);
    float4 ga = *(const float4*)&g[col];
    float4 gc = *(const float4*)&g[col + 4];
    float4 ba = *(const float4*)&be[col];
    float4 bc = *(const float4*)&be[col + 4];
    float gg[8] = {ga.x, ga.y, ga.z, ga.w, gc.x, gc.y, gc.z, gc.w};
    float bb[8] = {ba.x, ba.y, ba.z, ba.w, bc.x, bc.y, bc.z, bc.w};
    float y[8];
    f16x8 ohv, olv;
    #pragma unroll
    for (int i = 0; i < 8; ++i) {
        y[i] = d[i] * rstd * gg[i] + bb[i];
        _Float16 h2, l2; split_f16(y[i], h2, l2);
        ohv[i] = h2; olv[i] = l2;
    }
    *(f16x8*)&oh[rb] = ohv;
    *(f16x8*)&ol[rb] = olv;
    if (GATE) {
        float acc[E_] = {0.f, 0.f, 0.f, 0.f, 0.f, 0.f, 0.f, 0.f};
        #pragma unroll
        for (int i = 0; i < 8; ++i) {
            const float* gp = gw + (size_t)(col + i) * E_;
            float4 g0 = *(const float4*)gp;
            float4 g1 = *(const float4*)(gp + 4);
            acc[0] += y[i] * g0.x; acc[1] += y[i] * g0.y;
            acc[2] += y[i] * g0.z; acc[3] += y[i] * g0.w;
            acc[4] += y[i] * g1.x; acc[5] += y[i] * g1.y;
            acc[6] += y[i] * g1.z; acc[7] += y[i] * g1.w;
        }
        #pragma unroll
        for (int e = 0; e < E_; ++e)
            #pragma unroll
            for (int off = 32; off; off >>= 1) acc[e] += __shfl_xor(acc[e], off);
        if (lane == 0) {
            float* lp = lg + (size_t)row * E_;
            #pragma unroll
            for (int e = 0; e < E_; ++e) lp[e] = acc[e] + gbias[e];
        }
    }
}

// ---------------------------------------------------------------- MoE combine + residual + LN, wave-per-row
__global__ __launch_bounds__(256) void ln_add_moe(const _Float16* __restrict__ xh,
                                                  const _Float16* __restrict__ xl,
                                                  const float* __restrict__ eo,
                                                  const float* __restrict__ topv,
                                                  const int* __restrict__ route_row,
                                                  const float* __restrict__ g,
                                                  const float* __restrict__ be,
                                                  _Float16* __restrict__ oh,
                                                  _Float16* __restrict__ ol)
{
    int w = threadIdx.x >> 6, lane = threadIdx.x & 63;
    int row = blockIdx.x * 4 + w;
    int r0 = route_row[row * 2], r1 = route_row[row * 2 + 1];
    float w0 = topv[row * 2], w1 = topv[row * 2 + 1];
    int col = lane * 8;
    size_t rb = (size_t)row * D_ + col;
    f16x8 vh = *(const f16x8*)&xh[rb];
    f16x8 vl = *(const f16x8*)&xl[rb];
    const float* e0 = eo + (size_t)r0 * D_ + col;
    const float* e1 = eo + (size_t)r1 * D_ + col;
    float4 e0a = *(const float4*)e0;
    float4 e0b = *(const float4*)(e0 + 4);
    float4 e1a = *(const float4*)e1;
    float4 e1b = *(const float4*)(e1 + 4);
    float v[8];
    v[0] = (float)vh[0] + (float)vl[0] + w0 * e0a.x + w1 * e1a.x;
    v[1] = (float)vh[1] + (float)vl[1] + w0 * e0a.y + w1 * e1a.y;
    v[2] = (float)vh[2] + (float)vl[2] + w0 * e0a.z + w1 * e1a.z;
    v[3] = (float)vh[3] + (float)vl[3] + w0 * e0a.w + w1 * e1a.w;
    v[4] = (float)vh[4] + (float)vl[4] + w0 * e0b.x + w1 * e1b.x;
    v[5] = (float)vh[5] + (float)vl[5] + w0 * e0b.y + w1 * e1b.y;
    v[6] = (float)vh[6] + (float)vl[6] + w0 * e0b.z + w1 * e1b.z;
    v[7] = (float)vh[7] + (float)vl[7] + w0 * e0b.w + w1 * e1b.w;
    float s = 0.f;
    #pragma unroll
    for (int i = 0; i < 8; ++i) s += v[i];
    #pragma unroll
    for (int off = 32; off; off >>= 1) s += __shfl_xor(s, off);
    float m = s * (1.0f / 512.0f);
    float d[8];
    float q = 0.f;
    #pragma unroll
    for (int i = 0; i < 8; ++i) { d[i] = v[i] - m; q += d[i] * d[i]; }
    #pragma unroll
    for (int off = 32; off; off >>= 1) q += __shfl_xor(q, off);
    float rstd = rsqrtf(q * (1.0f / 512.0f) + 1e-5f);
    float4 ga = *(const float4*)&g[col];
    float4 gc = *(const float4*)&g[col + 4];
    float4 ba = *(const float4*)&be[col];
    float4 bc = *(const float4*)&be[col + 4];
    float gg[8] = {ga.x, ga.y, ga.z, ga.w, gc.x, gc.y, gc.z, gc.w};
    float bb[8] = {ba.x, ba.y, ba.z, ba.w, bc.x, bc.y, bc.z, bc.w};
    f16x8 ohv, olv;
    #pragma unroll
    for (int i = 0; i < 8; ++i) {
        float y = d[i] * rstd * gg[i] + bb[i];
        _Float16 h2, l2; split_f16(y, h2, l2);
        ohv[i] = h2; olv[i] = l2;
    }
    *(f16x8*)&oh[rb] = ohv;
    *(f16x8*)&ol[rb] = olv;
}

// ---------------------------------------------------------------- fused top2 + routing (64-granular, parallel prefix)
__global__ __launch_bounds__(1024) void gate_top2_routes(const float* __restrict__ lg,
                                                         float* __restrict__ topv,
                                                         int* __restrict__ route_tok,
                                                         int* __restrict__ route_row,
                                                         int* __restrict__ counts,
                                                         int* __restrict__ pad_base,
                                                         int* __restrict__ rb_expert)
{
    __shared__ int eid[NTOK * 2];
    __shared__ unsigned short chist[256][8];
    __shared__ unsigned short segb[8][16];
    __shared__ int pb[E_ + 1];
    __shared__ int cnt[E_];
    int t = threadIdx.x;
    #pragma unroll
    for (int s2 = 0; s2 < 2; ++s2) {
        int n = t * 2 + s2;
        float l0[E_], p[E_];
        float m = -1e30f;
        #pragma unroll
        for (int e = 0; e < E_; ++e) { l0[e] = lg[n * E_ + e]; m = fmaxf(m, l0[e]); }
        float su = 0.f;
        #pragma unroll
        for (int e = 0; e < E_; ++e) { p[e] = expf(l0[e] - m); su += p[e]; }
        float inv = 1.0f / su;
        int i1 = 0; float v1 = p[0];
        #pragma unroll
        for (int e = 1; e < E_; ++e) if (p[e] > v1) { v1 = p[e]; i1 = e; }
        int i2 = -1; float v2 = -1.f;
        #pragma unroll
        for (int e = 0; e < E_; ++e) if (e != i1 && p[e] > v2) { v2 = p[e]; i2 = e; }
        topv[n * 2] = v1 * inv; topv[n * 2 + 1] = v2 * inv;
        eid[n * 2] = i1; eid[n * 2 + 1] = i2;
    }
    #pragma unroll
    for (int g = 0; g < 5; ++g) route_tok[t + 1024 * g] = 0;
    __syncthreads();

    if (t < 256) {
        int r[16];
        #pragma unroll
        for (int i = 0; i < 16; ++i) r[i] = eid[t * 16 + i];
        #pragma unroll
        for (int e = 0; e < 8; ++e) {
            int h = 0;
            #pragma unroll
            for (int i = 0; i < 16; ++i) h += (r[i] == e) ? 1 : 0;
            chist[t][e] = (unsigned short)h;
        }
    }
    __syncthreads();

    if (t < 128) {
        int e = t >> 4, seg = t & 15;
        int s = 0;
        #pragma unroll
        for (int i = 0; i < 16; ++i) s += chist[seg * 16 + i][e];
        segb[e][seg] = (unsigned short)s;
    }
    __syncthreads();
    if (t < 8) {
        int run = 0;
        #pragma unroll
        for (int sg = 0; sg < 16; ++sg) {
            int v = segb[t][sg];
            segb[t][sg] = (unsigned short)run;
            run += v;
        }
        cnt[t] = run;
        counts[t] = run;
    }
    __syncthreads();
    if (t < 128) {
        int e = t >> 4, seg = t & 15;
        int run = segb[e][seg];
        #pragma unroll
        for (int i = 0; i < 16; ++i) {
            int c = seg * 16 + i;
            int v = chist[c][e];
            chist[c][e] = (unsigned short)run;
            run += v;
        }
    }
    __syncthreads();

    if (t == 0) {
        int pad = 0;
        for (int e = 0; e < 8; ++e) {
            pb[e] = pad;
            pad_base[e] = pad;
            int nb = (cnt[e] + 63) >> 6;
            for (int rb = 0; rb < nb; ++rb) rb_expert[(pad >> 6) + rb] = e;
            pad += nb << 6;
        }
        pb[8] = pad;
        pad_base[8] = pad;
    }
    __syncthreads();

    if (t < 256) {
        int r[16];
        #pragma unroll
        for (int i = 0; i < 16; ++i) r[i] = eid[t * 16 + i];
        #pragma unroll
        for (int e = 0; e < 8; ++e) {
            int o = pb[e] + chist[t][e];
            #pragma unroll
            for (int i = 0; i < 16; ++i) {
                if (r[i] == e) {
                    int slot = t * 16 + i;
                    route_tok[o] = slot >> 1;
                    route_row[slot] = o;
                    o++;
                }
            }
        }
    }
}

// ================================================================ host orchestration
extern "C" void kernel_launch(void* const* d_in, const int* in_sizes, int n_in,
                              void* d_out, int out_size, void* d_ws, size_t ws_size,
                              hipStream_t stream)
{
    const int*   src        = (const int*)  d_in[0];
    const int*   tgt        = (const int*)  d_in[1];
    const float* enc_emb    = (const float*)d_in[2];
    const float* dec_emb    = (const float*)d_in[3];
    const float* enc_attn_w = (const float*)d_in[4];
    const float* enc_attn_b = (const float*)d_in[5];
    const float* enc_ln_g   = (const float*)d_in[6];
    const float* enc_ln_b   = (const float*)d_in[7];
    const float* enc_gate_w = (const float*)d_in[8];
    const float* enc_gate_b = (const float*)d_in[9];
    const float* enc_w1     = (const float*)d_in[10];
    const float* enc_b1     = (const float*)d_in[11];
    const float* enc_w2     = (const float*)d_in[12];
    const float* enc_b2     = (const float*)d_in[13];
    const float* dec_sa_w   = (const float*)d_in[14];
    const float* dec_sa_b   = (const float*)d_in[15];
    const float* dec_ca_w   = (const float*)d_in[16];
    const float* dec_ca_b   = (const float*)d_in[17];
    const float* dec_ln_g   = (const float*)d_in[18];
    const float* dec_ln_b   = (const float*)d_in[19];
    const float* dec_gate_w = (const float*)d_in[20];
    const float* dec_gate_b = (const float*)d_in[21];
    const float* dec_w1     = (const float*)d_in[22];
    const float* dec_b1     = (const float*)d_in[23];
    const float* dec_w2     = (const float*)d_in[24];
    const float* dec_b2     = (const float*)d_in[25];
    const float* out_w      = (const float*)d_in[26];
    const float* out_b      = (const float*)d_in[27];
    float* out = (float*)d_out;

    // ---- d_out scratch (dead until final GEMM overwrites all of it)
    char* ob = (char*)d_out;
    size_t oc = 0;
    auto dalloc = [&](size_t bytes) { char* p = ob + oc; oc += (bytes + 255) & ~(size_t)255; return p; };
    _Float16* qkv_h  = (_Float16*)dalloc((size_t)NTOK * QLD * 2);
    _Float16* qkv_l  = (_Float16*)dalloc((size_t)NTOK * QLD * 2);
    _Float16* vt_h   = (_Float16*)dalloc((size_t)16 * 64 * 1024 * 2);
    _Float16* vt_l   = (_Float16*)dalloc((size_t)16 * 64 * 1024 * 2);
    float* aout  = (float*)dalloc((size_t)NTOK * D_ * 4);
    _Float16* ctx_h = (_Float16*)dalloc((size_t)NTOK * D_ * 2);
    _Float16* ctx_l = (_Float16*)dalloc((size_t)NTOK * D_ * 2);
    _Float16* encA_h = (_Float16*)dalloc((size_t)L_ * 4 * D_ * D_ * 2);
    _Float16* encA_l = (_Float16*)dalloc((size_t)L_ * 4 * D_ * D_ * 2);
    _Float16* saA_h  = (_Float16*)dalloc((size_t)L_ * 4 * D_ * D_ * 2);
    _Float16* saA_l  = (_Float16*)dalloc((size_t)L_ * 4 * D_ * D_ * 2);
    _Float16* caA_h  = (_Float16*)dalloc((size_t)L_ * 4 * D_ * D_ * 2);
    _Float16* caA_l  = (_Float16*)dalloc((size_t)L_ * 4 * D_ * D_ * 2);
    _Float16* xA_h = (_Float16*)dalloc((size_t)NTOK * D_ * 2);
    _Float16* xA_l = (_Float16*)dalloc((size_t)NTOK * D_ * 2);
    _Float16* xB_h = (_Float16*)dalloc((size_t)NTOK * D_ * 2);
    _Float16* xB_l = (_Float16*)dalloc((size_t)NTOK * D_ * 2);
    _Float16* yA_h = (_Float16*)dalloc((size_t)NTOK * D_ * 2);
    _Float16* yA_l = (_Float16*)dalloc((size_t)NTOK * D_ * 2);
    _Float16* yB_h = (_Float16*)dalloc((size_t)NTOK * D_ * 2);
    _Float16* yB_l = (_Float16*)dalloc((size_t)NTOK * D_ * 2);

    // ---- ws scratch (~360 MB of ~1 GB)
    char* wp = (char*)d_ws;
    size_t wc = 0;
    auto walloc = [&](size_t bytes) { char* p = wp + wc; wc += (bytes + 255) & ~(size_t)255; return p; };
    _Float16* outwT_h = (_Float16*)walloc((size_t)V_ * D_ * 2);
    _Float16* final_h = (_Float16*)walloc((size_t)NTOK * D_ * 2);
    size_t wsz = (size_t)L_ * E_ * D_ * F_;
    _Float16* ew1t_h = (_Float16*)walloc(wsz * 2);
    _Float16* ew1t_l = (_Float16*)walloc(wsz * 2);
    _Float16* ew2t_h = (_Float16*)walloc(wsz * 2);
    _Float16* ew2t_l = (_Float16*)walloc(wsz * 2);
    _Float16* dw1t_h = (_Float16*)walloc(wsz * 2);
    _Float16* dw1t_l = (_Float16*)walloc(wsz * 2);
    _Float16* dw2t_h = (_Float16*)walloc(wsz * 2);
    _Float16* dw2t_l = (_Float16*)walloc(wsz * 2);
    _Float16* hbuf_h  = (_Float16*)walloc((size_t)5120 * F_ * 2);
    _Float16* hbuf_l  = (_Float16*)walloc((size_t)5120 * F_ * 2);
    float*    eobuf   = (float*)walloc((size_t)5120 * D_ * 4);
    float* lg   = (float*)walloc((size_t)NTOK * E_ * 4);
    float* topv = (float*)walloc((size_t)NTOK * 2 * 4);
    int*   route_tok = (int*)walloc((size_t)5120 * 4);
    int*   route_row = (int*)walloc((size_t)NTOK * 2 * 4);
    int*   counts    = (int*)walloc(64);
    int*   pad_base  = (int*)walloc(64);
    int*   rb_expert = (int*)walloc((size_t)128 * 4);

    // ---- all weight transposes upfront
    transpose_w3<<<dim3(8, 8, 24), 256, 0, stream>>>(
        enc_attn_w, encA_h, encA_l, dec_sa_w, saA_h, saA_l, dec_ca_w, caA_h, caA_l);
    transpose_w<false><<<dim3(500, 8, 1), 256, 0, stream>>>(out_w, outwT_h, nullptr, D_, V_);
    transpose_w<true><<<dim3(32, 8, L_ * E_), 256, 0, stream>>>(enc_w1, ew1t_h, ew1t_l, D_, F_);
    transpose_w<true><<<dim3(8, 32, L_ * E_), 256, 0, stream>>>(enc_w2, ew2t_h, ew2t_l, F_, D_);
    transpose_w<true><<<dim3(32, 8, L_ * E_), 256, 0, stream>>>(dec_w1, dw1t_h, dw1t_l, D_, F_);
    transpose_w<true><<<dim3(8, 32, L_ * E_), 256, 0, stream>>>(dec_w2, dw2t_h, dw2t_l, F_, D_);

    auto run_mha = [&](const _Float16* q_h, const _Float16* q_l,
                       const _Float16* kv_h, const _Float16* kv_l,
                       const _Float16* wT_h, const _Float16* wT_l, const float* bt,
                       const int* ktoks, int causal, bool fused) {
        if (fused) {
            gemm_mfma<0, false, 2, 3, 64, 128><<<dim3(32, 12), 256, 0, stream>>>(
                q_h, q_l, wT_h, wT_l, bt, nullptr, qkv_h, qkv_l, vt_h, vt_l, 0,
                NTOK, D_, 1536, QLD, nullptr, nullptr, nullptr, nullptr);
        } else {
            gemm_mfma<0, false, 1, 3, 64, 64><<<dim3(32, 8), 256, 0, stream>>>(
                q_h, q_l, wT_h, wT_l, bt, nullptr, qkv_h, qkv_l, nullptr, nullptr, 0,
                NTOK, D_, 512, QLD, nullptr, nullptr, nullptr, nullptr);
            gemm_mfma<0, false, 2, 3, 64, 128><<<dim3(32, 8), 256, 0, stream>>>(
                kv_h, kv_l, wT_h + (size_t)D_ * D_, wT_l + (size_t)D_ * D_, bt + D_,
                nullptr, qkv_h, qkv_l, vt_h, vt_l, 512,
                NTOK, D_, 1024, QLD, nullptr, nullptr, nullptr, nullptr);
        }
        if (causal)
            attn_flash<1><<<dim3(16, 16), 512, 0, stream>>>(qkv_h, qkv_l, vt_h, vt_l, ktoks, ctx_h, ctx_l);
        else
            attn_flash<0><<<dim3(16, 16), 512, 0, stream>>>(qkv_h, qkv_l, vt_h, vt_l, ktoks, ctx_h, ctx_l);
        gemm_mfma<0, false, 0, 3, 64, 64><<<dim3(32, 8), 256, 0, stream>>>(
            ctx_h, ctx_l, wT_h + (size_t)3 * D_ * D_, wT_l + (size_t)3 * D_ * D_,
            bt + 3 * D_, aout, nullptr, nullptr, nullptr, nullptr, 0,
            NTOK, D_, 512, 512, nullptr, nullptr, nullptr, nullptr);
    };

    auto run_moe = [&](const _Float16* x_h, const _Float16* x_l,
                       const _Float16* w1h, const _Float16* w1l,
                       const _Float16* w2h, const _Float16* w2l,
                       const float* b1p, const float* b2p, bool p3) {
        gate_top2_routes<<<1, 1024, 0, stream>>>(lg, topv, route_tok, route_row, counts, pad_base, rb_expert);
        if (p3) {
            gemm_mfma<1, true, 1, 3, 64, 128><<<dim3(RB64, 16), 256, 0, stream>>>(
                x_h, x_l, w1h, w1l, b1p, nullptr, hbuf_h, hbuf_l, nullptr, nullptr, 0,
                0, D_, F_, F_, route_tok, rb_expert, pad_base, counts);
            gemm_mfma<2, false, 0, 3, 64, 64><<<dim3(RB64, 8), 256, 0, stream>>>(
                hbuf_h, hbuf_l, w2h, w2l, b2p, eobuf, nullptr, nullptr, nullptr, nullptr, 0,
                0, F_, D_, D_, route_tok, rb_expert, pad_base, counts);
        } else {
            gemm_mfma<1, true, 1, 1, 64, 128><<<dim3(RB64, 16), 256, 0, stream>>>(
                x_h, nullptr, w1h, nullptr, b1p, nullptr, hbuf_h, hbuf_l, nullptr, nullptr, 0,
                0, D_, F_, F_, route_tok, rb_expert, pad_base, counts);
            gemm_mfma<2, false, 0, 1, 64, 64><<<dim3(RB64, 8), 256, 0, stream>>>(
                hbuf_h, nullptr, w2h, nullptr, b2p, eobuf, nullptr, nullptr, nullptr, nullptr, 0,
                0, F_, D_, D_, route_tok, rb_expert, pad_base, counts);
        }
    };

    // ---------------- encoder ----------------
    embed_pe<<<B_ * S_, 256, 0, stream>>>(src, enc_emb, xA_h, xA_l, S_);
    _Float16* cur_h = xA_h; _Float16* cur_l = xA_l;
    _Float16* alt_h = xB_h; _Float16* alt_l = xB_l;
    for (int l = 0; l < L_; ++l) {
        run_mha(cur_h, cur_l, nullptr, nullptr,
                encA_h + (size_t)l * 4 * D_ * D_, encA_l + (size_t)l * 4 * D_ * D_,
                enc_attn_b + (size_t)l * 4 * D_, src, 0, true);
        ln_add<true><<<NTOK / 4, 256, 0, stream>>>(cur_h, cur_l, aout,
            enc_ln_g + (size_t)(l * 2 + 0) * D_, enc_ln_b + (size_t)(l * 2 + 0) * D_,
            alt_h, alt_l, enc_gate_w + (size_t)l * D_ * E_, enc_gate_b + (size_t)l * E_, lg);
        { _Float16* t = cur_h; cur_h = alt_h; alt_h = t; t = cur_l; cur_l = alt_l; alt_l = t; }
        run_moe(cur_h, cur_l,
                ew1t_h + (size_t)l * E_ * D_ * F_, ew1t_l + (size_t)l * E_ * D_ * F_,
                ew2t_h + (size_t)l * E_ * D_ * F_, ew2t_l + (size_t)l * E_ * D_ * F_,
                enc_b1 + (size_t)l * E_ * F_, enc_b2 + (size_t)l * E_ * D_, true);
        ln_add_moe<<<NTOK / 4, 256, 0, stream>>>(cur_h, cur_l, eobuf, topv, route_row,
            enc_ln_g + (size_t)(l * 2 + 1) * D_, enc_ln_b + (size_t)(l * 2 + 1) * D_,
            alt_h, alt_l);
        { _Float16* t = cur_h; cur_h = alt_h; alt_h = t; t = cur_l; cur_l = alt_l; alt_l = t; }
    }
    _Float16* enc_h = cur_h; _Float16* enc_l = cur_l;

    // ---------------- decoder ----------------
    embed_pe<<<B_ * T_, 256, 0, stream>>>(tgt, dec_emb, yA_h, yA_l, T_);
    _Float16* dc_h = yA_h; _Float16* dc_l = yA_l;
    _Float16* da_h = yB_h; _Float16* da_l = yB_l;
    for (int l = 0; l < L_; ++l) {
        run_mha(dc_h, dc_l, nullptr, nullptr,
                saA_h + (size_t)l * 4 * D_ * D_, saA_l + (size_t)l * 4 * D_ * D_,
                dec_sa_b + (size_t)l * 4 * D_, tgt, 1, true);
        ln_add<false><<<NTOK / 4, 256, 0, stream>>>(dc_h, dc_l, aout,
            dec_ln_g + (size_t)(l * 3 + 0) * D_, dec_ln_b + (size_t)(l * 3 + 0) * D_,
            da_h, da_l, nullptr, nullptr, nullptr);
        { _Float16* t = dc_h; dc_h = da_h; da_h = t; t = dc_l; dc_l = da_l; da_l = t; }
        run_mha(dc_h, dc_l, enc_h, enc_l,
                caA_h + (size_t)l * 4 * D_ * D_, caA_l + (size_t)l * 4 * D_ * D_,
                dec_ca_b + (size_t)l * 4 * D_, src, 0, false);
        ln_add<true><<<NTOK / 4, 256, 0, stream>>>(dc_h, dc_l, aout,
            dec_ln_g + (size_t)(l * 3 + 1) * D_, dec_ln_b + (size_t)(l * 3 + 1) * D_,
            da_h, da_l, dec_gate_w + (size_t)l * D_ * E_, dec_gate_b + (size_t)l * E_, lg);
        { _Float16* t = dc_h; dc_h = da_h; da_h = t; t = dc_l; dc_l = da_l; da_l = t; }
        bool last = (l == L_ - 1);
        run_moe(dc_h, dc_l,
                dw1t_h + (size_t)l * E_ * D_ * F_, dw1t_l + (size_t)l * E_ * D_ * F_,
                dw2t_h + (size_t)l * E_ * D_ * F_, dw2t_l + (size_t)l * E_ * D_ * F_,
                dec_b1 + (size_t)l * E_ * F_, dec_b2 + (size_t)l * E_ * D_, !last);
        ln_add_moe<<<NTOK / 4, 256, 0, stream>>>(dc_h, dc_l, eobuf, topv, route_row,
            dec_ln_g + (size_t)(l * 3 + 2) * D_, dec_ln_b + (size_t)(l * 3 + 2) * D_,
            last ? final_h : da_h, da_l);
        { _Float16* t = dc_h; dc_h = da_h; da_h = t; t = dc_l; dc_l = da_l; da_l = t; }
    }

    // ---------------- final projection (single-pass f16 MFMA; overwrites all of d_out)
    gemm_mfma<0, false, 0, 1, 128, 128><<<dim3(NTOK / 128, V_ / 128), 256, 0, stream>>>(
        final_h, nullptr, outwT_h, nullptr, out_b, out, nullptr, nullptr, nullptr, nullptr, 0,
        NTOK, D_, V_, V_, nullptr, nullptr, nullptr, nullptr);
}